// Round 3
// baseline (323.908 us; speedup 1.0000x reference)
//
#include <hip/hip_runtime.h>

// Problem constants (from reference): B=16, C=1, H=1024, W=1024, fp32.
#define HH 1024
#define WW 1024

__device__ __forceinline__ float4 fmax4(float4 a, float4 b) {
    return make_float4(fmaxf(a.x, b.x), fmaxf(a.y, b.y),
                       fmaxf(a.z, b.z), fmaxf(a.w, b.w));
}

__device__ __forceinline__ float loss_elem(float x, float t, float dil) {
    // weight: target>0.5 -> 20, elif dilated>0.5 -> 5, else 1
    float w = (t > 0.5f) ? 20.0f : ((dil > 0.5f) ? 5.0f : 1.0f);
    // BCE with logits: max(x,0) - x*t + log1p(exp(-|x|))
    // softplus(-|x|) via HW v_exp_f32 / v_log_f32: arg of log in [1,2],
    // rel err ~1e-5 (passed with absmax 0.0 in R2).
    float a  = fabsf(x);
    float sp = __logf(1.0f + __expf(-a));
    return w * (fmaxf(x, 0.0f) - x * t + sp);
}

__global__ __launch_bounds__(256) void dilatedweightBCE_kernel(
        const float* __restrict__ pred,
        const float* __restrict__ target,
        float* __restrict__ out,
        float inv_n) {
    // One block per (image b, row h): 256 threads x float4 = 1024 cols.
    // Dilation fully in registers: vertical max from 3 row loads (re-reads of
    // adjacent rows hit L2/L3 -- R1 showed FETCH == ideal), horizontal halo
    // via intra-wave shfl; the 6 wave-boundary lanes per row patch their halo
    // with 3 scalar cache-hit loads. No LDS / no barrier until the final
    // 4-slot reduction. VGPR stays low -> 8 waves/SIMD.
    __shared__ float swave[4];

    const int tid = threadIdx.x;
    const int h   = blockIdx.x;
    const int b   = blockIdx.y;
    const size_t rowbase = ((size_t)b * HH + h) * WW;

    const bool has_up = (h > 0);          // block-uniform branches
    const bool has_dn = (h < HH - 1);

    float4 t0 = ((const float4*)(target + rowbase))[tid];
    float4 vm = t0;
    if (has_up) vm = fmax4(vm, ((const float4*)(target + rowbase - WW))[tid]);
    if (has_dn) vm = fmax4(vm, ((const float4*)(target + rowbase + WW))[tid]);
    float4 x = ((const float4*)(pred + rowbase))[tid];

    // horizontal halo: left = vmax at col c-1, right = vmax at col c+4
    float l = __shfl_up(vm.w, 1);
    float r = __shfl_down(vm.x, 1);

    const int lane = tid & 63;
    const int c    = tid * 4;
    if (lane == 0) {             // 1 active lane/wave: patch left halo
        l = 0.0f;
        if (c > 0) {
            float v = target[rowbase + c - 1];
            if (has_up) v = fmaxf(v, target[rowbase - WW + c - 1]);
            if (has_dn) v = fmaxf(v, target[rowbase + WW + c - 1]);
            l = v;
        }
    }
    if (lane == 63) {            // 1 active lane/wave: patch right halo
        r = 0.0f;
        if (c + 4 < WW) {
            float v = target[rowbase + c + 4];
            if (has_up) v = fmaxf(v, target[rowbase - WW + c + 4]);
            if (has_dn) v = fmaxf(v, target[rowbase + WW + c + 4]);
            r = v;
        }
    }

    float d0 = fmaxf(l,    fmaxf(vm.x, vm.y));
    float d1 = fmaxf(vm.x, fmaxf(vm.y, vm.z));
    float d2 = fmaxf(vm.y, fmaxf(vm.z, vm.w));
    float d3 = fmaxf(vm.z, fmaxf(vm.w, r));

    float s = 0.0f;
    s += loss_elem(x.x, t0.x, d0);
    s += loss_elem(x.y, t0.y, d1);
    s += loss_elem(x.z, t0.z, d2);
    s += loss_elem(x.w, t0.w, d3);

    // wave (64-lane) shuffle reduction, then cross-wave via LDS
    #pragma unroll
    for (int off = 32; off > 0; off >>= 1)
        s += __shfl_down(s, off);

    const int wave = tid >> 6;
    if (lane == 0) swave[wave] = s;
    __syncthreads();
    if (tid == 0) {
        float tot = swave[0] + swave[1] + swave[2] + swave[3];
        atomicAdd(out, tot * inv_n);
    }
}

extern "C" void kernel_launch(void* const* d_in, const int* in_sizes, int n_in,
                              void* d_out, int out_size, void* d_ws, size_t ws_size,
                              hipStream_t stream) {
    const float* pred   = (const float*)d_in[0];
    const float* target = (const float*)d_in[1];
    float* out = (float*)d_out;

    const int n  = in_sizes[0];              // B*C*H*W
    const int Bn = n / (HH * WW);            // batch (16)

    // d_out is re-poisoned to 0xAA before every timed launch; zero it ourselves.
    hipMemsetAsync(d_out, 0, sizeof(float), stream);

    dim3 grid(HH, Bn);
    dilatedweightBCE_kernel<<<grid, 256, 0, stream>>>(pred, target, out,
                                                      1.0f / (float)n);
}

// Round 4
// 162.089 us; speedup vs baseline: 1.9983x; 1.9983x over previous
//
#include <hip/hip_runtime.h>

// Problem constants (from reference): B=16, C=1, H=1024, W=1024, fp32.
#define HH 1024
#define WW 1024

__device__ __forceinline__ float4 fmax4(float4 a, float4 b) {
    return make_float4(fmaxf(a.x, b.x), fmaxf(a.y, b.y),
                       fmaxf(a.z, b.z), fmaxf(a.w, b.w));
}

__device__ __forceinline__ float loss_elem(float x, float t, float dil) {
    // weight: target>0.5 -> 20, elif dilated>0.5 -> 5, else 1
    float w = (t > 0.5f) ? 20.0f : ((dil > 0.5f) ? 5.0f : 1.0f);
    // BCE with logits: max(x,0) - x*t + log1p(exp(-|x|))
    // softplus(-|x|) via HW v_exp_f32 / v_log_f32 (absmax 0.0 in R2/R3).
    float a  = fabsf(x);
    float sp = __logf(1.0f + __expf(-a));
    return w * (fmaxf(x, 0.0f) - x * t + sp);
}

__global__ __launch_bounds__(256) void dilatedweightBCE_main(
        const float* __restrict__ pred,
        const float* __restrict__ target,
        float* __restrict__ partial) {
    // One block per (image b, row h): 256 threads x float4 = 1024 cols.
    // Dilation fully in registers (R3 scheme): vertical max from 3 row loads
    // (adjacent-row re-reads hit L2/L3 -- FETCH == ideal in R1/R3),
    // horizontal halo via intra-wave shfl + 6 boundary-lane patch loads.
    // NO atomics: partial sum stored to a disjoint slot per block.
    __shared__ float swave[4];

    const int tid = threadIdx.x;
    const int h   = blockIdx.x;
    const int b   = blockIdx.y;
    const size_t rowbase = ((size_t)b * HH + h) * WW;

    const bool has_up = (h > 0);          // block-uniform branches
    const bool has_dn = (h < HH - 1);

    float4 t0 = ((const float4*)(target + rowbase))[tid];
    float4 vm = t0;
    if (has_up) vm = fmax4(vm, ((const float4*)(target + rowbase - WW))[tid]);
    if (has_dn) vm = fmax4(vm, ((const float4*)(target + rowbase + WW))[tid]);
    float4 x = ((const float4*)(pred + rowbase))[tid];

    // horizontal halo: left = vmax at col c-1, right = vmax at col c+4
    float l = __shfl_up(vm.w, 1);
    float r = __shfl_down(vm.x, 1);

    const int lane = tid & 63;
    const int c    = tid * 4;
    if (lane == 0) {             // patch left halo (1 lane/wave)
        l = 0.0f;
        if (c > 0) {
            float v = target[rowbase + c - 1];
            if (has_up) v = fmaxf(v, target[rowbase - WW + c - 1]);
            if (has_dn) v = fmaxf(v, target[rowbase + WW + c - 1]);
            l = v;
        }
    }
    if (lane == 63) {            // patch right halo (1 lane/wave)
        r = 0.0f;
        if (c + 4 < WW) {
            float v = target[rowbase + c + 4];
            if (has_up) v = fmaxf(v, target[rowbase - WW + c + 4]);
            if (has_dn) v = fmaxf(v, target[rowbase + WW + c + 4]);
            r = v;
        }
    }

    float d0 = fmaxf(l,    fmaxf(vm.x, vm.y));
    float d1 = fmaxf(vm.x, fmaxf(vm.y, vm.z));
    float d2 = fmaxf(vm.y, fmaxf(vm.z, vm.w));
    float d3 = fmaxf(vm.z, fmaxf(vm.w, r));

    float s = 0.0f;
    s += loss_elem(x.x, t0.x, d0);
    s += loss_elem(x.y, t0.y, d1);
    s += loss_elem(x.z, t0.z, d2);
    s += loss_elem(x.w, t0.w, d3);

    // wave (64-lane) shuffle reduction, then cross-wave via LDS
    #pragma unroll
    for (int off = 32; off > 0; off >>= 1)
        s += __shfl_down(s, off);

    const int wave = tid >> 6;
    if (lane == 0) swave[wave] = s;
    __syncthreads();
    if (tid == 0) {
        // one plain store per block into a disjoint slot -- zero contention
        partial[blockIdx.y * gridDim.x + blockIdx.x] =
            swave[0] + swave[1] + swave[2] + swave[3];
    }
}

__global__ __launch_bounds__(256) void dilatedweightBCE_reduce(
        const float* __restrict__ partial,
        float* __restrict__ out,
        int npart4,            // number of float4 chunks
        float inv_n) {
    __shared__ float swave[4];
    const int tid = threadIdx.x;

    float s = 0.0f;
    const float4* p4 = (const float4*)partial;
    for (int i = tid; i < npart4; i += 256) {
        float4 v = p4[i];
        s += v.x + v.y + v.z + v.w;
    }

    #pragma unroll
    for (int off = 32; off > 0; off >>= 1)
        s += __shfl_down(s, off);

    const int wave = tid >> 6;
    const int lane = tid & 63;
    if (lane == 0) swave[wave] = s;
    __syncthreads();
    if (tid == 0)
        out[0] = (swave[0] + swave[1] + swave[2] + swave[3]) * inv_n;
}

extern "C" void kernel_launch(void* const* d_in, const int* in_sizes, int n_in,
                              void* d_out, int out_size, void* d_ws, size_t ws_size,
                              hipStream_t stream) {
    const float* pred   = (const float*)d_in[0];
    const float* target = (const float*)d_in[1];
    float* out     = (float*)d_out;
    float* partial = (float*)d_ws;           // 16384 floats = 64 KB scratch

    const int n  = in_sizes[0];              // B*C*H*W
    const int Bn = n / (HH * WW);            // batch (16)
    const int nblocks = HH * Bn;             // 16384

    dim3 grid(HH, Bn);
    dilatedweightBCE_main<<<grid, 256, 0, stream>>>(pred, target, partial);
    dilatedweightBCE_reduce<<<1, 256, 0, stream>>>(partial, out,
                                                   nblocks / 4, 1.0f / (float)n);
}